// Round 2
// baseline (5416.345 us; speedup 1.0000x reference)
//
#include <hip/hip_runtime.h>

#define NA 100000
#define NE 300000
#define D  32
#define BD 16
#define STEPS 4

// ---------------------------------------------------------------------------
// zb[a,i] = sum_j b_bond[i*32+j] * h[a,j]   (bias-matrix contribution, per atom)
// ---------------------------------------------------------------------------
__global__ __launch_bounds__(256, 4) void zb_kernel(
    const float* __restrict__ h, const float* __restrict__ bb, float* __restrict__ zb)
{
    __shared__ float lb[1024];
    for (int t = threadIdx.x; t < 1024; t += 256) lb[t] = bb[t];
    __syncthreads();

    int a = blockIdx.x * 256 + threadIdx.x;
    if (a >= NA) return;

    float hv[32];
    const float4* h4 = reinterpret_cast<const float4*>(h + (size_t)a * 32);
#pragma unroll
    for (int j4 = 0; j4 < 8; ++j4) {
        float4 t = h4[j4];
        hv[4*j4+0] = t.x; hv[4*j4+1] = t.y; hv[4*j4+2] = t.z; hv[4*j4+3] = t.w;
    }
    const float4* lb4 = reinterpret_cast<const float4*>(lb);
#pragma unroll 1
    for (int ib = 0; ib < 4; ++ib) {
        float s[8];
#pragma unroll
        for (int ii = 0; ii < 8; ++ii) s[ii] = 0.f;
#pragma unroll
        for (int j4 = 0; j4 < 8; ++j4) {
#pragma unroll
            for (int ii = 0; ii < 8; ++ii) {
                float4 w = lb4[(ib*8+ii)*8 + j4];
                s[ii] += w.x*hv[4*j4] + w.y*hv[4*j4+1] + w.z*hv[4*j4+2] + w.w*hv[4*j4+3];
            }
        }
        float4* dst = reinterpret_cast<float4*>(zb + (size_t)a*32 + ib*8);
        dst[0] = make_float4(s[0], s[1], s[2], s[3]);
        dst[1] = make_float4(s[4], s[5], s[6], s[7]);
    }
}

// ---------------------------------------------------------------------------
// msg: per edge e, acc[i] = zb[nbr,i] + sum_k bond[e,k] * dot(Wb[k, i*32:], h[nbr])
//      atomically added into agg[dst]. W_bond staged in LDS (64 KB), broadcast
//      ds_read_b128; 2 edges per lane so each W read feeds 8 FMAs.
// ---------------------------------------------------------------------------
__global__ __launch_bounds__(256, 2) void msg_kernel(
    const float* __restrict__ h, const float* __restrict__ zb,
    const float* __restrict__ bond, const int* __restrict__ pair,
    const float* __restrict__ Wb, float* __restrict__ agg)
{
    __shared__ float lw[16 * 1024];   // 64 KB exactly
    {
        const float4* src = reinterpret_cast<const float4*>(Wb);
        float4* dst = reinterpret_cast<float4*>(lw);
        for (int t = threadIdx.x; t < 4096; t += 256) dst[t] = src[t];
    }
    __syncthreads();

    int e0 = blockIdx.x * 512 + threadIdx.x;
    int e1 = e0 + 256;
    bool v0 = e0 < NE, v1 = e1 < NE;
    int eL0 = v0 ? e0 : 0;
    int eL1 = v1 ? e1 : 0;

    int2 p0 = reinterpret_cast<const int2*>(pair)[eL0];
    int2 p1 = reinterpret_cast<const int2*>(pair)[eL1];
    int d0 = p0.x, n0 = p0.y;
    int d1 = p1.x, n1 = p1.y;

    float hv0[32], hv1[32];
    {
        const float4* a4 = reinterpret_cast<const float4*>(h + (size_t)n0 * 32);
        const float4* b4 = reinterpret_cast<const float4*>(h + (size_t)n1 * 32);
#pragma unroll
        for (int j4 = 0; j4 < 8; ++j4) {
            float4 t = a4[j4];
            hv0[4*j4+0] = t.x; hv0[4*j4+1] = t.y; hv0[4*j4+2] = t.z; hv0[4*j4+3] = t.w;
            float4 u = b4[j4];
            hv1[4*j4+0] = u.x; hv1[4*j4+1] = u.y; hv1[4*j4+2] = u.z; hv1[4*j4+3] = u.w;
        }
    }

#pragma unroll 1
    for (int ib = 0; ib < 4; ++ib) {
        float a0[8], a1[8];
        {
            const float4* z0 = reinterpret_cast<const float4*>(zb + (size_t)n0*32 + ib*8);
            const float4* z1 = reinterpret_cast<const float4*>(zb + (size_t)n1*32 + ib*8);
            float4 t0 = z0[0], t1 = z0[1];
            a0[0]=t0.x; a0[1]=t0.y; a0[2]=t0.z; a0[3]=t0.w;
            a0[4]=t1.x; a0[5]=t1.y; a0[6]=t1.z; a0[7]=t1.w;
            float4 u0 = z1[0], u1 = z1[1];
            a1[0]=u0.x; a1[1]=u0.y; a1[2]=u0.z; a1[3]=u0.w;
            a1[4]=u1.x; a1[5]=u1.y; a1[6]=u1.z; a1[7]=u1.w;
        }
        const float4* wb4 = reinterpret_cast<const float4*>(lw) + ib*64; // rows i = ib*8..ib*8+7

#pragma unroll 1
        for (int k = 0; k < 16; ++k) {
            float c0 = bond[(size_t)eL0*16 + k];   // reloaded (L1) to avoid dynamic reg indexing
            float c1 = bond[(size_t)eL1*16 + k];
            const float4* wr = wb4 + k*256;
            float s0[8], s1[8];
#pragma unroll
            for (int ii = 0; ii < 8; ++ii) { s0[ii] = 0.f; s1[ii] = 0.f; }
#pragma unroll
            for (int j4 = 0; j4 < 8; ++j4) {
#pragma unroll
                for (int ii = 0; ii < 8; ++ii) {
                    float4 w = wr[ii*8 + j4];   // wave-uniform broadcast
                    s0[ii] += w.x*hv0[4*j4] + w.y*hv0[4*j4+1] + w.z*hv0[4*j4+2] + w.w*hv0[4*j4+3];
                    s1[ii] += w.x*hv1[4*j4] + w.y*hv1[4*j4+1] + w.z*hv1[4*j4+2] + w.w*hv1[4*j4+3];
                }
            }
#pragma unroll
            for (int ii = 0; ii < 8; ++ii) { a0[ii] += c0*s0[ii]; a1[ii] += c1*s1[ii]; }
        }

        if (v0) {
#pragma unroll
            for (int ii = 0; ii < 8; ++ii)
                atomicAdd(&agg[(size_t)d0*32 + ib*8 + ii], a0[ii]);
        }
        if (v1) {
#pragma unroll
            for (int ii = 0; ii < 8; ++ii)
                atomicAdd(&agg[(size_t)d1*32 + ib*8 + ii], a1[ii]);
        }
    }
}

// ---------------------------------------------------------------------------
// GRU cell, one atom per lane; Wih/Whh staged in LDS, broadcast reads.
// ---------------------------------------------------------------------------
__global__ __launch_bounds__(256, 4) void gru_kernel(
    const float* __restrict__ agg, const float* __restrict__ hprev,
    const float* __restrict__ Wih, const float* __restrict__ Whh,
    const float* __restrict__ bih, const float* __restrict__ bhh,
    float* __restrict__ hout)
{
    __shared__ float lih[96*32];
    __shared__ float lhh[96*32];
    {
        const float4* s1 = reinterpret_cast<const float4*>(Wih);
        const float4* s2 = reinterpret_cast<const float4*>(Whh);
        float4* q1 = reinterpret_cast<float4*>(lih);
        float4* q2 = reinterpret_cast<float4*>(lhh);
        for (int t = threadIdx.x; t < 768; t += 256) { q1[t] = s1[t]; q2[t] = s2[t]; }
    }
    __syncthreads();

    int a = blockIdx.x * 256 + threadIdx.x;
    if (a >= NA) return;

    float x[32], hv[32];
    {
        const float4* x4 = reinterpret_cast<const float4*>(agg + (size_t)a * 32);
        const float4* h4 = reinterpret_cast<const float4*>(hprev + (size_t)a * 32);
#pragma unroll
        for (int j4 = 0; j4 < 8; ++j4) {
            float4 t = x4[j4];
            x[4*j4+0] = t.x; x[4*j4+1] = t.y; x[4*j4+2] = t.z; x[4*j4+3] = t.w;
            float4 u = h4[j4];
            hv[4*j4+0] = u.x; hv[4*j4+1] = u.y; hv[4*j4+2] = u.z; hv[4*j4+3] = u.w;
        }
    }
    const float4* i4  = reinterpret_cast<const float4*>(lih);
    const float4* hh4 = reinterpret_cast<const float4*>(lhh);

#pragma unroll 1
    for (int ib = 0; ib < 16; ++ib) {  // i-blocks of 2
        float gr[2], gz[2], gn[2], hr[2], hz[2], hn[2];
#pragma unroll
        for (int ii = 0; ii < 2; ++ii) {
            int r = ib*2 + ii;
            gr[ii] = bih[r]; gz[ii] = bih[32+r]; gn[ii] = bih[64+r];
            hr[ii] = bhh[r]; hz[ii] = bhh[32+r]; hn[ii] = bhh[64+r];
        }
#pragma unroll
        for (int j4 = 0; j4 < 8; ++j4) {
#pragma unroll
            for (int ii = 0; ii < 2; ++ii) {
                int r = ib*2 + ii;
                float4 w;
                w = i4[(r     )*8 + j4]; gr[ii] += w.x*x[4*j4] + w.y*x[4*j4+1] + w.z*x[4*j4+2] + w.w*x[4*j4+3];
                w = i4[(32 + r)*8 + j4]; gz[ii] += w.x*x[4*j4] + w.y*x[4*j4+1] + w.z*x[4*j4+2] + w.w*x[4*j4+3];
                w = i4[(64 + r)*8 + j4]; gn[ii] += w.x*x[4*j4] + w.y*x[4*j4+1] + w.z*x[4*j4+2] + w.w*x[4*j4+3];
                w = hh4[(r     )*8 + j4]; hr[ii] += w.x*hv[4*j4] + w.y*hv[4*j4+1] + w.z*hv[4*j4+2] + w.w*hv[4*j4+3];
                w = hh4[(32 + r)*8 + j4]; hz[ii] += w.x*hv[4*j4] + w.y*hv[4*j4+1] + w.z*hv[4*j4+2] + w.w*hv[4*j4+3];
                w = hh4[(64 + r)*8 + j4]; hn[ii] += w.x*hv[4*j4] + w.y*hv[4*j4+1] + w.z*hv[4*j4+2] + w.w*hv[4*j4+3];
            }
        }
        float o[2];
#pragma unroll
        for (int ii = 0; ii < 2; ++ii) {
            float r = 1.f / (1.f + __expf(-(gr[ii] + hr[ii])));
            float z = 1.f / (1.f + __expf(-(gz[ii] + hz[ii])));
            float n = tanhf(gn[ii] + r * hn[ii]);
            float hi = hprev[(size_t)a*32 + ib*2 + ii];  // L1 reload, avoids dyn reg index
            o[ii] = (1.f - z) * n + z * hi;
        }
        *reinterpret_cast<float2*>(hout + (size_t)a*32 + ib*2) = make_float2(o[0], o[1]);
    }
}

extern "C" void kernel_launch(void* const* d_in, const int* in_sizes, int n_in,
                              void* d_out, int out_size, void* d_ws, size_t ws_size,
                              hipStream_t stream)
{
    const float* atom = (const float*)d_in[0];
    const float* bond = (const float*)d_in[1];
    const int*   pair = (const int*)  d_in[2];
    const float* Wb   = (const float*)d_in[3];
    const float* bb   = (const float*)d_in[4];
    const float* W_ih = (const float*)d_in[5];
    const float* W_hh = (const float*)d_in[6];
    const float* b_ih = (const float*)d_in[7];
    const float* b_hh = (const float*)d_in[8];
    float* out = (float*)d_out;

    const size_t HB = (size_t)NA * D * sizeof(float);
    float* agg = (float*)d_ws;
    float* h0  = (float*)((char*)d_ws + HB);
    float* h1  = (float*)((char*)d_ws + 2 * HB);
    float* zb  = (float*)((char*)d_ws + 3 * HB);
    float* hbufs[2] = { h0, h1 };

    const int atom_blocks = (NA + 255) / 256;
    const int msg_blocks  = (NE + 511) / 512;

    const float* hcur = atom;
    for (int s = 0; s < STEPS; ++s) {
        hipMemsetAsync(agg, 0, HB, stream);
        zb_kernel<<<atom_blocks, 256, 0, stream>>>(hcur, bb, zb);
        msg_kernel<<<msg_blocks, 256, 0, stream>>>(hcur, zb, bond, pair, Wb, agg);
        float* hnext = (s == STEPS - 1) ? out : hbufs[s & 1];
        gru_kernel<<<atom_blocks, 256, 0, stream>>>(agg, hcur, W_ih, W_hh, b_ih, b_hh, hnext);
        hcur = hnext;
    }
}

// Round 3
// 658.795 us; speedup vs baseline: 8.2216x; 8.2216x over previous
//
#include <hip/hip_runtime.h>

#define NA 100000
#define NE 300000
#define STEPS 4
#define NTILES (NE / 16)        // 18750
#define WPITCH 40               // padded j-pitch (elements) for Wbt rows

using short8 = __attribute__((ext_vector_type(8))) short;
using f32x4  = __attribute__((ext_vector_type(4))) float;

__device__ __forceinline__ unsigned short f2bf(float x) {
    unsigned int u = __float_as_uint(x);
    unsigned int r = (u + 0x7FFFu + ((u >> 16) & 1u)) >> 16;
    return (unsigned short)r;
}

// ---------------------------------------------------------------------------
// fp32 -> bf16 (RNE) bulk convert, float4/ushort4 vectorized
// ---------------------------------------------------------------------------
__global__ __launch_bounds__(256) void conv_kernel(
    const float* __restrict__ h, unsigned short* __restrict__ hb)
{
    int t = blockIdx.x * 256 + threadIdx.x;          // t < NA*32/4
    if (t >= NA * 32 / 4) return;
    float4 v = reinterpret_cast<const float4*>(h)[t];
    ushort4 o;
    o.x = f2bf(v.x); o.y = f2bf(v.y); o.z = f2bf(v.z); o.w = f2bf(v.w);
    reinterpret_cast<ushort4*>(hb)[t] = o;
}

// ---------------------------------------------------------------------------
// Build Wbt (bf16) in B-fragment-friendly layout: Wbt[k][i][j] with j-pitch 40,
// value = Wb[k][i*32+j] for k<16, bb[i*32+j] for k==16 (bias matrix).
// ---------------------------------------------------------------------------
__global__ __launch_bounds__(256) void prep_kernel(
    const float* __restrict__ Wb, const float* __restrict__ bb,
    unsigned short* __restrict__ Wbt)
{
    int t = blockIdx.x * 256 + threadIdx.x;          // t < 17*32*32
    if (t >= 17 * 32 * 32) return;
    int j = t & 31, i = (t >> 5) & 31, k = t >> 10;
    float v = (k < 16) ? Wb[k * 1024 + i * 32 + j] : bb[i * 32 + j];
    Wbt[(k * 32 + i) * WPITCH + j] = f2bf(v);
}

// ---------------------------------------------------------------------------
// msg via MFMA: one wave = 16 edges. D[e,i] = sum_j A[e,j] B[j,i] per k-matrix;
// acc += c[e,k] * D; bias matrix (k=16) MFMA'd directly into acc. fp32 atomics.
// ---------------------------------------------------------------------------
__global__ __launch_bounds__(256) void msg_kernel(
    const unsigned short* __restrict__ hb,   // [NA][32] bf16
    const float* __restrict__ bond,          // [NE][16]
    const int* __restrict__ pair,            // [NE][2] (dst, nbr)
    const unsigned short* __restrict__ Wbt,  // [17][32][WPITCH] bf16
    float* __restrict__ agg)                 // [NA][32] fp32, pre-zeroed
{
    __shared__ unsigned short lw[17 * 32 * WPITCH];  // 43520 B
    for (int t = threadIdx.x; t < 17 * 32 * WPITCH / 8; t += 256)
        reinterpret_cast<short8*>(lw)[t] = reinterpret_cast<const short8*>(Wbt)[t];
    __syncthreads();

    int wave = threadIdx.x >> 6;
    int lane = threadIdx.x & 63;
    int tile = blockIdx.x * 4 + wave;
    if (tile >= NTILES) return;

    int base = tile * 16;
    int col  = lane & 15;        // A-row (edge) / B-col (i) / D-col
    int kg   = lane >> 4;        // k-group (8 consecutive k per group)
    int row0 = kg * 4;           // D rows held by this lane: row0..row0+3

    int2 p = reinterpret_cast<const int2*>(pair)[base + col];  // (dst, nbr) of edge 'col'
    int nbr = p.y;

    // A fragment: 8 consecutive bf16 of h[nbr] at j = kg*8
    short8 afrag = *reinterpret_cast<const short8*>(hb + (size_t)nbr * 32 + kg * 8);

    // this lane's own edge's 16 bond coefficients (registers, static-indexed)
    float c[16];
    {
        const float4* b4 = reinterpret_cast<const float4*>(bond + (size_t)(base + col) * 16);
        float4 t0 = b4[0], t1 = b4[1], t2 = b4[2], t3 = b4[3];
        c[0]=t0.x; c[1]=t0.y; c[2]=t0.z; c[3]=t0.w;
        c[4]=t1.x; c[5]=t1.y; c[6]=t1.z; c[7]=t1.w;
        c[8]=t2.x; c[9]=t2.y; c[10]=t2.z; c[11]=t2.w;
        c[12]=t3.x; c[13]=t3.y; c[14]=t3.z; c[15]=t3.w;
    }

    f32x4 acc0 = {0.f, 0.f, 0.f, 0.f};
    f32x4 acc1 = {0.f, 0.f, 0.f, 0.f};

    // bias matrix (k=16): unscaled, accumulate directly
    {
        const short8* b0 = reinterpret_cast<const short8*>(lw + (16 * 32 + col) * WPITCH + kg * 8);
        const short8* b1 = reinterpret_cast<const short8*>(lw + (16 * 32 + 16 + col) * WPITCH + kg * 8);
        acc0 = __builtin_amdgcn_mfma_f32_16x16x32_bf16(afrag, *b0, acc0, 0, 0, 0);
        acc1 = __builtin_amdgcn_mfma_f32_16x16x32_bf16(afrag, *b1, acc1, 0, 0, 0);
    }

#pragma unroll
    for (int km = 0; km < 16; ++km) {
        short8 b0 = *reinterpret_cast<const short8*>(lw + (km * 32 + col) * WPITCH + kg * 8);
        short8 b1 = *reinterpret_cast<const short8*>(lw + (km * 32 + 16 + col) * WPITCH + kg * 8);
        f32x4 z = {0.f, 0.f, 0.f, 0.f};
        f32x4 d0 = __builtin_amdgcn_mfma_f32_16x16x32_bf16(afrag, b0, z, 0, 0, 0);
        f32x4 d1 = __builtin_amdgcn_mfma_f32_16x16x32_bf16(afrag, b1, z, 0, 0, 0);
        float c0 = __shfl(c[km], row0 + 0);
        float c1 = __shfl(c[km], row0 + 1);
        float c2 = __shfl(c[km], row0 + 2);
        float c3 = __shfl(c[km], row0 + 3);
        acc0[0] += c0 * d0[0]; acc0[1] += c1 * d0[1];
        acc0[2] += c2 * d0[2]; acc0[3] += c3 * d0[3];
        acc1[0] += c0 * d1[0]; acc1[1] += c1 * d1[1];
        acc1[2] += c2 * d1[2]; acc1[3] += c3 * d1[3];
    }

#pragma unroll
    for (int r = 0; r < 4; ++r) {
        int dr = __shfl(p.x, row0 + r);   // dst of edge (row0+r)
        atomicAdd(&agg[(size_t)dr * 32 + col],      acc0[r]);
        atomicAdd(&agg[(size_t)dr * 32 + 16 + col], acc1[r]);
    }
}

// ---------------------------------------------------------------------------
// GRU cell — round-1 structure (proven), plus bf16 h output for next step.
// ---------------------------------------------------------------------------
__global__ __launch_bounds__(256) void gru_kernel(
    const float* __restrict__ agg, const float* __restrict__ hprev,
    const float* __restrict__ Wih, const float* __restrict__ Whh,
    const float* __restrict__ bih, const float* __restrict__ bhh,
    float* __restrict__ hout, unsigned short* __restrict__ hbf)
{
    int a = blockIdx.x * 256 + threadIdx.x;
    if (a >= NA) return;

    float x[32], hv[32];
#pragma unroll
    for (int j4 = 0; j4 < 8; ++j4) {
        float4 t = *reinterpret_cast<const float4*>(agg + (size_t)a * 32 + 4 * j4);
        x[4*j4+0] = t.x; x[4*j4+1] = t.y; x[4*j4+2] = t.z; x[4*j4+3] = t.w;
        float4 u = *reinterpret_cast<const float4*>(hprev + (size_t)a * 32 + 4 * j4);
        hv[4*j4+0] = u.x; hv[4*j4+1] = u.y; hv[4*j4+2] = u.z; hv[4*j4+3] = u.w;
    }

#pragma unroll 1
    for (int i = 0; i < 32; ++i) {
        float ir = bih[i], iz = bih[32 + i], inn = bih[64 + i];
        float hr = bhh[i], hz = bhh[32 + i], hn = bhh[64 + i];
#pragma unroll
        for (int j = 0; j < 32; ++j) {
            ir  += Wih[(i     ) * 32 + j] * x[j];
            iz  += Wih[(32 + i) * 32 + j] * x[j];
            inn += Wih[(64 + i) * 32 + j] * x[j];
            hr  += Whh[(i     ) * 32 + j] * hv[j];
            hz  += Whh[(32 + i) * 32 + j] * hv[j];
            hn  += Whh[(64 + i) * 32 + j] * hv[j];
        }
        float r = 1.f / (1.f + __expf(-(ir + hr)));
        float z = 1.f / (1.f + __expf(-(iz + hz)));
        float n = tanhf(inn + r * hn);
        float hi = hprev[(size_t)a * 32 + i];   // L1 reload, avoids dyn reg index
        float o = (1.f - z) * n + z * hi;
        hout[(size_t)a * 32 + i] = o;
        hbf[(size_t)a * 32 + i] = f2bf(o);
    }
}

extern "C" void kernel_launch(void* const* d_in, const int* in_sizes, int n_in,
                              void* d_out, int out_size, void* d_ws, size_t ws_size,
                              hipStream_t stream)
{
    const float* atom = (const float*)d_in[0];
    const float* bond = (const float*)d_in[1];
    const int*   pair = (const int*)  d_in[2];
    const float* Wb   = (const float*)d_in[3];
    const float* bb   = (const float*)d_in[4];
    const float* W_ih = (const float*)d_in[5];
    const float* W_hh = (const float*)d_in[6];
    const float* b_ih = (const float*)d_in[7];
    const float* b_hh = (const float*)d_in[8];
    float* out = (float*)d_out;

    const size_t HB = (size_t)NA * 32 * sizeof(float);      // 12.8 MB
    float*          agg  = (float*)d_ws;
    float*          h0   = (float*)((char*)d_ws + HB);
    float*          h1   = (float*)((char*)d_ws + 2 * HB);
    unsigned short* hbf  = (unsigned short*)((char*)d_ws + 3 * HB);          // 6.4 MB
    unsigned short* Wbt  = (unsigned short*)((char*)d_ws + 3 * HB + HB / 2); // 43.5 KB
    float* hbufs[2] = { h0, h1 };

    const int conv_blocks = (NA * 32 / 4 + 255) / 256;
    const int prep_blocks = (17 * 32 * 32 + 255) / 256;
    const int msg_blocks  = (NTILES + 3) / 4;
    const int gru_blocks  = (NA + 255) / 256;

    prep_kernel<<<prep_blocks, 256, 0, stream>>>(Wb, bb, Wbt);
    conv_kernel<<<conv_blocks, 256, 0, stream>>>(atom, hbf);

    const float* hcur = atom;
    for (int s = 0; s < STEPS; ++s) {
        hipMemsetAsync(agg, 0, HB, stream);
        msg_kernel<<<msg_blocks, 256, 0, stream>>>(hbf, bond, pair, Wbt, agg);
        float* hnext = (s == STEPS - 1) ? out : hbufs[s & 1];
        gru_kernel<<<gru_blocks, 256, 0, stream>>>(agg, hcur, W_ih, W_hh, b_ih, b_hh, hnext, hbf);
        hcur = hnext;
    }
}

// Round 4
// 508.026 us; speedup vs baseline: 10.6616x; 1.2968x over previous
//
#include <hip/hip_runtime.h>

#define NA 100000
#define NE 300000
#define STEPS 4
#define NTILES (NE / 16)        // 18750
#define WPITCH 40               // padded j-pitch (elements) for Wbt rows

using short8 = __attribute__((ext_vector_type(8))) short;
using f32x4  = __attribute__((ext_vector_type(4))) float;

__device__ __forceinline__ unsigned short f2bf(float x) {
    unsigned int u = __float_as_uint(x);
    unsigned int r = (u + 0x7FFFu + ((u >> 16) & 1u)) >> 16;
    return (unsigned short)r;
}

// ---------------------------------------------------------------------------
// fp32 -> bf16 (RNE) bulk convert, float4/ushort4 vectorized
// ---------------------------------------------------------------------------
__global__ __launch_bounds__(256) void conv_kernel(
    const float* __restrict__ h, unsigned short* __restrict__ hb)
{
    int t = blockIdx.x * 256 + threadIdx.x;          // t < NA*32/4
    if (t >= NA * 32 / 4) return;
    float4 v = reinterpret_cast<const float4*>(h)[t];
    ushort4 o;
    o.x = f2bf(v.x); o.y = f2bf(v.y); o.z = f2bf(v.z); o.w = f2bf(v.w);
    reinterpret_cast<ushort4*>(hb)[t] = o;
}

// ---------------------------------------------------------------------------
// Build Wbt (bf16): Wbt[k][i][j], j-pitch 40; k==16 is the bias matrix.
// ---------------------------------------------------------------------------
__global__ __launch_bounds__(256) void prep_kernel(
    const float* __restrict__ Wb, const float* __restrict__ bb,
    unsigned short* __restrict__ Wbt)
{
    int t = blockIdx.x * 256 + threadIdx.x;          // t < 17*32*32
    if (t >= 17 * 32 * 32) return;
    int j = t & 31, i = (t >> 5) & 31, k = t >> 10;
    float v = (k < 16) ? Wb[k * 1024 + i * 32 + j] : bb[i * 32 + j];
    Wbt[(k * 32 + i) * WPITCH + j] = f2bf(v);
}

// ---------------------------------------------------------------------------
// msg via MFMA: one wave = 16 edges. D[e,i] = sum_j A[e,j] B[j,i] per k-matrix;
// acc += c[e,k] * D; bias matrix (k=16) MFMA'd directly into acc. fp32 atomics.
// ---------------------------------------------------------------------------
__global__ __launch_bounds__(256) void msg_kernel(
    const unsigned short* __restrict__ hb,   // [NA][32] bf16
    const float* __restrict__ bond,          // [NE][16]
    const int* __restrict__ pair,            // [NE][2] (dst, nbr)
    const unsigned short* __restrict__ Wbt,  // [17][32][WPITCH] bf16
    float* __restrict__ agg)                 // [NA][32] fp32, pre-zeroed
{
    __shared__ unsigned short lw[17 * 32 * WPITCH];  // 43520 B
    for (int t = threadIdx.x; t < 17 * 32 * WPITCH / 8; t += 256)
        reinterpret_cast<short8*>(lw)[t] = reinterpret_cast<const short8*>(Wbt)[t];
    __syncthreads();

    int wave = threadIdx.x >> 6;
    int lane = threadIdx.x & 63;
    int tile = blockIdx.x * 4 + wave;
    if (tile >= NTILES) return;

    int base = tile * 16;
    int col  = lane & 15;        // A-row (edge) / B-col (i) / D-col
    int kg   = lane >> 4;        // k-group
    int row0 = kg * 4;           // D rows held by this lane

    int2 p = reinterpret_cast<const int2*>(pair)[base + col];
    int nbr = p.y;

    short8 afrag = *reinterpret_cast<const short8*>(hb + (size_t)nbr * 32 + kg * 8);

    float c[16];
    {
        const float4* b4 = reinterpret_cast<const float4*>(bond + (size_t)(base + col) * 16);
        float4 t0 = b4[0], t1 = b4[1], t2 = b4[2], t3 = b4[3];
        c[0]=t0.x; c[1]=t0.y; c[2]=t0.z; c[3]=t0.w;
        c[4]=t1.x; c[5]=t1.y; c[6]=t1.z; c[7]=t1.w;
        c[8]=t2.x; c[9]=t2.y; c[10]=t2.z; c[11]=t2.w;
        c[12]=t3.x; c[13]=t3.y; c[14]=t3.z; c[15]=t3.w;
    }

    f32x4 acc0 = {0.f, 0.f, 0.f, 0.f};
    f32x4 acc1 = {0.f, 0.f, 0.f, 0.f};

    {
        const short8* b0 = reinterpret_cast<const short8*>(lw + (16 * 32 + col) * WPITCH + kg * 8);
        const short8* b1 = reinterpret_cast<const short8*>(lw + (16 * 32 + 16 + col) * WPITCH + kg * 8);
        acc0 = __builtin_amdgcn_mfma_f32_16x16x32_bf16(afrag, *b0, acc0, 0, 0, 0);
        acc1 = __builtin_amdgcn_mfma_f32_16x16x32_bf16(afrag, *b1, acc1, 0, 0, 0);
    }

#pragma unroll
    for (int km = 0; km < 16; ++km) {
        short8 b0 = *reinterpret_cast<const short8*>(lw + (km * 32 + col) * WPITCH + kg * 8);
        short8 b1 = *reinterpret_cast<const short8*>(lw + (km * 32 + 16 + col) * WPITCH + kg * 8);
        f32x4 z = {0.f, 0.f, 0.f, 0.f};
        f32x4 d0 = __builtin_amdgcn_mfma_f32_16x16x32_bf16(afrag, b0, z, 0, 0, 0);
        f32x4 d1 = __builtin_amdgcn_mfma_f32_16x16x32_bf16(afrag, b1, z, 0, 0, 0);
        float c0 = __shfl(c[km], row0 + 0);
        float c1 = __shfl(c[km], row0 + 1);
        float c2 = __shfl(c[km], row0 + 2);
        float c3 = __shfl(c[km], row0 + 3);
        acc0[0] += c0 * d0[0]; acc0[1] += c1 * d0[1];
        acc0[2] += c2 * d0[2]; acc0[3] += c3 * d0[3];
        acc1[0] += c0 * d1[0]; acc1[1] += c1 * d1[1];
        acc1[2] += c2 * d1[2]; acc1[3] += c3 * d1[3];
    }

#pragma unroll
    for (int r = 0; r < 4; ++r) {
        int dr = __shfl(p.x, row0 + r);
        atomicAdd(&agg[(size_t)dr * 32 + col],      acc0[r]);
        atomicAdd(&agg[(size_t)dr * 32 + 16 + col], acc1[r]);
    }
}

// ---------------------------------------------------------------------------
// GRU cell — one atom per lane; outputs staged through padded LDS, then
// block-coalesced float4/ushort4 stores (kills the 17x write amplification).
// ---------------------------------------------------------------------------
__global__ __launch_bounds__(256) void gru_kernel(
    const float* __restrict__ agg, const float* __restrict__ hprev,
    const float* __restrict__ Wih, const float* __restrict__ Whh,
    const float* __restrict__ bih, const float* __restrict__ bhh,
    float* __restrict__ hout, unsigned short* __restrict__ hbf)
{
    __shared__ float lo[256 * 33];   // padded: bank (t+i)%32, conflict-free

    int a0 = blockIdx.x * 256;                 // block's first atom
    int t  = threadIdx.x;
    int a  = a0 + t;
    int ac = (a < NA) ? a : (NA - 1);          // clamp; no early return (barrier!)

    float x[32], hv[32];
#pragma unroll
    for (int j4 = 0; j4 < 8; ++j4) {
        float4 v = *reinterpret_cast<const float4*>(agg + (size_t)ac * 32 + 4 * j4);
        x[4*j4+0] = v.x; x[4*j4+1] = v.y; x[4*j4+2] = v.z; x[4*j4+3] = v.w;
        float4 u = *reinterpret_cast<const float4*>(hprev + (size_t)ac * 32 + 4 * j4);
        hv[4*j4+0] = u.x; hv[4*j4+1] = u.y; hv[4*j4+2] = u.z; hv[4*j4+3] = u.w;
    }

#pragma unroll 1
    for (int i = 0; i < 32; ++i) {
        float ir = bih[i], iz = bih[32 + i], inn = bih[64 + i];
        float hr = bhh[i], hz = bhh[32 + i], hn = bhh[64 + i];
#pragma unroll
        for (int j = 0; j < 32; ++j) {
            ir  += Wih[(i     ) * 32 + j] * x[j];
            iz  += Wih[(32 + i) * 32 + j] * x[j];
            inn += Wih[(64 + i) * 32 + j] * x[j];
            hr  += Whh[(i     ) * 32 + j] * hv[j];
            hz  += Whh[(32 + i) * 32 + j] * hv[j];
            hn  += Whh[(64 + i) * 32 + j] * hv[j];
        }
        float r = 1.f / (1.f + __expf(-(ir + hr)));
        float z = 1.f / (1.f + __expf(-(iz + hz)));
        float n = tanhf(inn + r * hn);
        float hi = hprev[(size_t)ac * 32 + i];   // L1 reload, avoids dyn reg index
        lo[t * 33 + i] = (1.f - z) * n + z * hi;
    }
    __syncthreads();

    // coalesced write-out: 2048 float4 per block, 8 per thread
    const float4* o4base = reinterpret_cast<const float4*>(hout);  // unused; silence
    (void)o4base;
#pragma unroll
    for (int cch = 0; cch < 8; ++cch) {
        int f4 = cch * 256 + t;                // float4 index within block
        int al = f4 >> 3;                      // local atom
        int i4 = (f4 & 7) * 4;                 // element offset
        if (a0 + al < NA) {
            float4 v;
            v.x = lo[al * 33 + i4 + 0];
            v.y = lo[al * 33 + i4 + 1];
            v.z = lo[al * 33 + i4 + 2];
            v.w = lo[al * 33 + i4 + 3];
            *reinterpret_cast<float4*>(hout + (size_t)(a0 + al) * 32 + i4) = v;
            ushort4 o;
            o.x = f2bf(v.x); o.y = f2bf(v.y); o.z = f2bf(v.z); o.w = f2bf(v.w);
            *reinterpret_cast<ushort4*>(hbf + (size_t)(a0 + al) * 32 + i4) = o;
        }
    }
}

extern "C" void kernel_launch(void* const* d_in, const int* in_sizes, int n_in,
                              void* d_out, int out_size, void* d_ws, size_t ws_size,
                              hipStream_t stream)
{
    const float* atom = (const float*)d_in[0];
    const float* bond = (const float*)d_in[1];
    const int*   pair = (const int*)  d_in[2];
    const float* Wb   = (const float*)d_in[3];
    const float* bb   = (const float*)d_in[4];
    const float* W_ih = (const float*)d_in[5];
    const float* W_hh = (const float*)d_in[6];
    const float* b_ih = (const float*)d_in[7];
    const float* b_hh = (const float*)d_in[8];
    float* out = (float*)d_out;

    const size_t HB = (size_t)NA * 32 * sizeof(float);      // 12.8 MB
    float*          agg  = (float*)d_ws;
    float*          h0   = (float*)((char*)d_ws + HB);
    float*          h1   = (float*)((char*)d_ws + 2 * HB);
    unsigned short* hbf  = (unsigned short*)((char*)d_ws + 3 * HB);          // 6.4 MB
    unsigned short* Wbt  = (unsigned short*)((char*)d_ws + 3 * HB + HB / 2); // 43.5 KB
    float* hbufs[2] = { h0, h1 };

    const int conv_blocks = (NA * 32 / 4 + 255) / 256;
    const int prep_blocks = (17 * 32 * 32 + 255) / 256;
    const int msg_blocks  = (NTILES + 3) / 4;
    const int gru_blocks  = (NA + 255) / 256;

    prep_kernel<<<prep_blocks, 256, 0, stream>>>(Wb, bb, Wbt);
    conv_kernel<<<conv_blocks, 256, 0, stream>>>(atom, hbf);

    const float* hcur = atom;
    for (int s = 0; s < STEPS; ++s) {
        hipMemsetAsync(agg, 0, HB, stream);
        msg_kernel<<<msg_blocks, 256, 0, stream>>>(hbf, bond, pair, Wbt, agg);
        float* hnext = (s == STEPS - 1) ? out : hbufs[s & 1];
        gru_kernel<<<gru_blocks, 256, 0, stream>>>(agg, hcur, W_ih, W_hh, b_ih, b_hh, hnext, hbf);
        hcur = hnext;
    }
}

// Round 5
// 318.341 us; speedup vs baseline: 17.0143x; 1.5959x over previous
//
#include <hip/hip_runtime.h>

#define NA 100000
#define NE 300000
#define STEPS 4
#define NTILES (NE / 16)        // 18750 (exact)
#define ATILES (NA / 16)        // 6250  (exact)
#define WPITCH 40               // padded j-pitch (elements) for Wbt rows

using short8 = __attribute__((ext_vector_type(8))) short;
using f32x4  = __attribute__((ext_vector_type(4))) float;

__device__ __forceinline__ unsigned short f2bf(float x) {
    unsigned int u = __float_as_uint(x);
    unsigned int r = (u + 0x7FFFu + ((u >> 16) & 1u)) >> 16;
    return (unsigned short)r;
}

// ---------------------------------------------------------------------------
// fp32 -> bf16 bulk convert (step-0 h)
// ---------------------------------------------------------------------------
__global__ __launch_bounds__(256) void conv_kernel(
    const float* __restrict__ h, unsigned short* __restrict__ hb)
{
    int t = blockIdx.x * 256 + threadIdx.x;
    if (t >= NA * 32 / 4) return;
    float4 v = reinterpret_cast<const float4*>(h)[t];
    ushort4 o;
    o.x = f2bf(v.x); o.y = f2bf(v.y); o.z = f2bf(v.z); o.w = f2bf(v.w);
    reinterpret_cast<ushort4*>(hb)[t] = o;
}

// ---------------------------------------------------------------------------
// Preconvert weights: Wbt[k][i][j] (pitch 40, k=16 is bias matrix),
// plus bf16 copies of W_ih / W_hh ([96][32], row-major).
// ---------------------------------------------------------------------------
__global__ __launch_bounds__(256) void prep_kernel(
    const float* __restrict__ Wb, const float* __restrict__ bb,
    const float* __restrict__ Wih, const float* __restrict__ Whh,
    unsigned short* __restrict__ Wbt,
    unsigned short* __restrict__ Wihb, unsigned short* __restrict__ Whhb)
{
    int t = blockIdx.x * 256 + threadIdx.x;     // < 17*32*32 + 2*96*32 = 23552
    if (t < 17 * 32 * 32) {
        int j = t & 31, i = (t >> 5) & 31, k = t >> 10;
        float v = (k < 16) ? Wb[k * 1024 + i * 32 + j] : bb[i * 32 + j];
        Wbt[(k * 32 + i) * WPITCH + j] = f2bf(v);
    } else if (t < 17 * 32 * 32 + 3072) {
        int u = t - 17 * 32 * 32;
        Wihb[u] = f2bf(Wih[u]);
    } else if (t < 17 * 32 * 32 + 6144) {
        int u = t - 17 * 32 * 32 - 3072;
        Whhb[u] = f2bf(Whh[u]);
    }
}

// ---------------------------------------------------------------------------
// msg via MFMA (unchanged from round 3/4): one wave = 16 edges.
// ---------------------------------------------------------------------------
__global__ __launch_bounds__(256) void msg_kernel(
    const unsigned short* __restrict__ hb,   // [NA][32] bf16
    const float* __restrict__ bond,          // [NE][16]
    const int* __restrict__ pair,            // [NE][2] (dst, nbr)
    const unsigned short* __restrict__ Wbt,  // [17][32][WPITCH] bf16
    float* __restrict__ agg)                 // [NA][32] fp32, pre-zeroed
{
    __shared__ unsigned short lw[17 * 32 * WPITCH];  // 43520 B
    for (int t = threadIdx.x; t < 17 * 32 * WPITCH / 8; t += 256)
        reinterpret_cast<short8*>(lw)[t] = reinterpret_cast<const short8*>(Wbt)[t];
    __syncthreads();

    int wave = threadIdx.x >> 6;
    int lane = threadIdx.x & 63;
    int tile = blockIdx.x * 4 + wave;
    if (tile >= NTILES) return;

    int base = tile * 16;
    int col  = lane & 15;
    int kg   = lane >> 4;
    int row0 = kg * 4;

    int2 p = reinterpret_cast<const int2*>(pair)[base + col];
    int nbr = p.y;

    short8 afrag = *reinterpret_cast<const short8*>(hb + (size_t)nbr * 32 + kg * 8);

    float c[16];
    {
        const float4* b4 = reinterpret_cast<const float4*>(bond + (size_t)(base + col) * 16);
        float4 t0 = b4[0], t1 = b4[1], t2 = b4[2], t3 = b4[3];
        c[0]=t0.x; c[1]=t0.y; c[2]=t0.z; c[3]=t0.w;
        c[4]=t1.x; c[5]=t1.y; c[6]=t1.z; c[7]=t1.w;
        c[8]=t2.x; c[9]=t2.y; c[10]=t2.z; c[11]=t2.w;
        c[12]=t3.x; c[13]=t3.y; c[14]=t3.z; c[15]=t3.w;
    }

    f32x4 acc0 = {0.f, 0.f, 0.f, 0.f};
    f32x4 acc1 = {0.f, 0.f, 0.f, 0.f};

    {
        const short8* b0 = reinterpret_cast<const short8*>(lw + (16 * 32 + col) * WPITCH + kg * 8);
        const short8* b1 = reinterpret_cast<const short8*>(lw + (16 * 32 + 16 + col) * WPITCH + kg * 8);
        acc0 = __builtin_amdgcn_mfma_f32_16x16x32_bf16(afrag, *b0, acc0, 0, 0, 0);
        acc1 = __builtin_amdgcn_mfma_f32_16x16x32_bf16(afrag, *b1, acc1, 0, 0, 0);
    }

#pragma unroll
    for (int km = 0; km < 16; ++km) {
        short8 b0 = *reinterpret_cast<const short8*>(lw + (km * 32 + col) * WPITCH + kg * 8);
        short8 b1 = *reinterpret_cast<const short8*>(lw + (km * 32 + 16 + col) * WPITCH + kg * 8);
        f32x4 z = {0.f, 0.f, 0.f, 0.f};
        f32x4 d0 = __builtin_amdgcn_mfma_f32_16x16x32_bf16(afrag, b0, z, 0, 0, 0);
        f32x4 d1 = __builtin_amdgcn_mfma_f32_16x16x32_bf16(afrag, b1, z, 0, 0, 0);
        float c0 = __shfl(c[km], row0 + 0);
        float c1 = __shfl(c[km], row0 + 1);
        float c2 = __shfl(c[km], row0 + 2);
        float c3 = __shfl(c[km], row0 + 3);
        acc0[0] += c0 * d0[0]; acc0[1] += c1 * d0[1];
        acc0[2] += c2 * d0[2]; acc0[3] += c3 * d0[3];
        acc1[0] += c0 * d1[0]; acc1[1] += c1 * d1[1];
        acc1[2] += c2 * d1[2]; acc1[3] += c3 * d1[3];
    }

#pragma unroll
    for (int r = 0; r < 4; ++r) {
        int dr = __shfl(p.x, row0 + r);
        atomicAdd(&agg[(size_t)dr * 32 + col],      acc0[r]);
        atomicAdd(&agg[(size_t)dr * 32 + 16 + col], acc1[r]);
    }
}

// ---------------------------------------------------------------------------
// GRU via MFMA: one wave = 16 atoms. gi = x@Wih^T, gh = h@Whh^T as 12 MFMAs;
// gates land lane-local across accumulator tiles; fp32 blend with hprev.
// ---------------------------------------------------------------------------
__global__ __launch_bounds__(256) void gru_kernel(
    const float* __restrict__ agg,            // [NA][32] fp32
    const float* __restrict__ hprev,          // [NA][32] fp32
    const unsigned short* __restrict__ hb,    // [NA][32] bf16 (same h as hprev)
    const unsigned short* __restrict__ Wihb,  // [96][32] bf16
    const unsigned short* __restrict__ Whhb,  // [96][32] bf16
    const float* __restrict__ bih, const float* __restrict__ bhh,
    float* __restrict__ hout, unsigned short* __restrict__ hbf)
{
    int wave = threadIdx.x >> 6;
    int lane = threadIdx.x & 63;
    int tile = blockIdx.x * 4 + wave;
    if (tile >= ATILES) return;

    int base = tile * 16;
    int col  = lane & 15;        // A-row select for frag load; D-col (output idx)
    int kg   = lane >> 4;        // k-group

    // A-frag for x: agg row (base+col), j = kg*8..+8, fp32 -> bf16
    short8 xfrag;
    {
        const float4* x4 = reinterpret_cast<const float4*>(agg + (size_t)(base + col) * 32 + kg * 8);
        float4 a = x4[0], b = x4[1];
        xfrag[0] = (short)f2bf(a.x); xfrag[1] = (short)f2bf(a.y);
        xfrag[2] = (short)f2bf(a.z); xfrag[3] = (short)f2bf(a.w);
        xfrag[4] = (short)f2bf(b.x); xfrag[5] = (short)f2bf(b.y);
        xfrag[6] = (short)f2bf(b.z); xfrag[7] = (short)f2bf(b.w);
    }
    // A-frag for h: already bf16
    short8 hfrag = *reinterpret_cast<const short8*>(hb + (size_t)(base + col) * 32 + kg * 8);

    // 12 MFMAs: 6 output tiles (96 outputs) x {gi, gh}
    f32x4 gi[6], gh[6];
#pragma unroll
    for (int t = 0; t < 6; ++t) {
        short8 bi = *reinterpret_cast<const short8*>(Wihb + (size_t)(t * 16 + col) * 32 + kg * 8);
        short8 bh = *reinterpret_cast<const short8*>(Whhb + (size_t)(t * 16 + col) * 32 + kg * 8);
        f32x4 z = {0.f, 0.f, 0.f, 0.f};
        gi[t] = __builtin_amdgcn_mfma_f32_16x16x32_bf16(xfrag, bi, z, 0, 0, 0);
        gh[t] = __builtin_amdgcn_mfma_f32_16x16x32_bf16(hfrag, bh, z, 0, 0, 0);
    }

    // Nonlinearity + blend. Lane holds atoms m = kg*4+reg, output n = hh*16+col.
#pragma unroll
    for (int hh = 0; hh < 2; ++hh) {
        int i  = hh * 16 + col;
        float br  = bih[i]      + bhh[i];        // folded r bias
        float bz  = bih[32 + i] + bhh[32 + i];   // folded z bias
        float bin = bih[64 + i];
        float bhn = bhh[64 + i];
#pragma unroll
        for (int reg = 0; reg < 4; ++reg) {
            int a = base + kg * 4 + reg;
            float r = 1.f / (1.f + __expf(-(gi[hh][reg] + gh[hh][reg] + br)));
            float z = 1.f / (1.f + __expf(-(gi[2 + hh][reg] + gh[2 + hh][reg] + bz)));
            float n = tanhf(gi[4 + hh][reg] + bin + r * (gh[4 + hh][reg] + bhn));
            float hp = hprev[(size_t)a * 32 + i];
            float o  = (1.f - z) * n + z * hp;
            hout[(size_t)a * 32 + i] = o;          // 16 lanes x 4B = full 64B line
            hbf[(size_t)a * 32 + i]  = f2bf(o);
        }
    }
}

extern "C" void kernel_launch(void* const* d_in, const int* in_sizes, int n_in,
                              void* d_out, int out_size, void* d_ws, size_t ws_size,
                              hipStream_t stream)
{
    const float* atom = (const float*)d_in[0];
    const float* bond = (const float*)d_in[1];
    const int*   pair = (const int*)  d_in[2];
    const float* Wb   = (const float*)d_in[3];
    const float* bb   = (const float*)d_in[4];
    const float* W_ih = (const float*)d_in[5];
    const float* W_hh = (const float*)d_in[6];
    const float* b_ih = (const float*)d_in[7];
    const float* b_hh = (const float*)d_in[8];
    float* out = (float*)d_out;

    const size_t HB = (size_t)NA * 32 * sizeof(float);      // 12.8 MB
    float*          agg  = (float*)d_ws;
    float*          h0   = (float*)((char*)d_ws + HB);
    float*          h1   = (float*)((char*)d_ws + 2 * HB);
    unsigned short* hbf  = (unsigned short*)((char*)d_ws + 3 * HB);           // 6.4 MB
    unsigned short* Wbt  = (unsigned short*)((char*)d_ws + 3 * HB + HB / 2);  // 43.5 KB
    unsigned short* Wihb = Wbt + 17 * 32 * WPITCH;
    unsigned short* Whhb = Wihb + 96 * 32;
    float* hbufs[2] = { h0, h1 };

    const int conv_blocks = (NA * 32 / 4 + 255) / 256;
    const int prep_blocks = (17 * 32 * 32 + 6144 + 255) / 256;
    const int msg_blocks  = (NTILES + 3) / 4;
    const int gru_blocks  = (ATILES + 3) / 4;

    prep_kernel<<<prep_blocks, 256, 0, stream>>>(Wb, bb, W_ih, W_hh, Wbt, Wihb, Whhb);
    conv_kernel<<<conv_blocks, 256, 0, stream>>>(atom, hbf);

    const float* hcur = atom;
    for (int s = 0; s < STEPS; ++s) {
        hipMemsetAsync(agg, 0, HB, stream);
        msg_kernel<<<msg_blocks, 256, 0, stream>>>(hbf, bond, pair, Wbt, agg);
        float* hnext = (s == STEPS - 1) ? out : hbufs[s & 1];
        gru_kernel<<<gru_blocks, 256, 0, stream>>>(agg, hcur, hbf, Wihb, Whhb,
                                                   b_ih, b_hh, hnext, hbf);
        hcur = hnext;
    }
}

// Round 6
// 280.623 us; speedup vs baseline: 19.3012x; 1.1344x over previous
//
#include <hip/hip_runtime.h>

#define NA 100000
#define NE 300000
#define STEPS 4
#define NTILES (NE / 16)        // 18750 (exact)
#define NJOBS  (NTILES / 2)     // 9375  (2 tiles per wave)
#define ATILES (NA / 16)        // 6250  (exact)
#define WPITCH 40               // padded j-pitch (elements) for Wbt rows

typedef _Float16 f16;
typedef _Float16 half8 __attribute__((ext_vector_type(8)));
using f32x4  = __attribute__((ext_vector_type(4))) float;
using short8 = __attribute__((ext_vector_type(8))) short;

// ---------------------------------------------------------------------------
// fp32 -> fp16 bulk convert (step-0 h)
// ---------------------------------------------------------------------------
__global__ __launch_bounds__(256) void conv_kernel(
    const float* __restrict__ h, f16* __restrict__ hb)
{
    int t = blockIdx.x * 256 + threadIdx.x;
    if (t >= NA * 32 / 4) return;
    float4 v = reinterpret_cast<const float4*>(h)[t];
    f16 o0 = (f16)v.x, o1 = (f16)v.y, o2 = (f16)v.z, o3 = (f16)v.w;
    ushort4 u;
    u.x = __builtin_bit_cast(unsigned short, o0);
    u.y = __builtin_bit_cast(unsigned short, o1);
    u.z = __builtin_bit_cast(unsigned short, o2);
    u.w = __builtin_bit_cast(unsigned short, o3);
    reinterpret_cast<ushort4*>(hb)[t] = u;
}

// ---------------------------------------------------------------------------
// Preconvert weights to fp16: Wbt[k][i][j] (pitch 40, k=16 is bias matrix),
// Wihb / Whhb = [96][32] row-major.
// ---------------------------------------------------------------------------
__global__ __launch_bounds__(256) void prep_kernel(
    const float* __restrict__ Wb, const float* __restrict__ bb,
    const float* __restrict__ Wih, const float* __restrict__ Whh,
    f16* __restrict__ Wbt, f16* __restrict__ Wihb, f16* __restrict__ Whhb)
{
    int t = blockIdx.x * 256 + threadIdx.x;     // < 17*32*32 + 2*96*32 = 23552
    if (t < 17 * 32 * 32) {
        int j = t & 31, i = (t >> 5) & 31, k = t >> 10;
        float v = (k < 16) ? Wb[k * 1024 + i * 32 + j] : bb[i * 32 + j];
        Wbt[(k * 32 + i) * WPITCH + j] = (f16)v;
    } else if (t < 17 * 32 * 32 + 3072) {
        int u = t - 17 * 32 * 32;
        Wihb[u] = (f16)Wih[u];
    } else if (t < 17 * 32 * 32 + 6144) {
        int u = t - 17 * 32 * 32 - 3072;
        Whhb[u] = (f16)Whh[u];
    }
}

// ---------------------------------------------------------------------------
// msg: c folded into the A-operand. One wave = 32 edges (2 tiles).
// msg[e,i] = sum_{s,j} (c[e,s]*h[e,j]) * Wb[s,i,j]  -> 17-step chained MFMA.
// B-fragments shared by both tiles; no shfl in the main loop; fp32 atomics.
// ---------------------------------------------------------------------------
__global__ __launch_bounds__(256) void msg_kernel(
    const f16* __restrict__ hb,              // [NA][32] fp16
    const float* __restrict__ bond,          // [NE][16]
    const int* __restrict__ pair,            // [NE][2] (dst, nbr)
    const f16* __restrict__ Wbt,             // [17][32][WPITCH] fp16
    float* __restrict__ agg)                 // [NA][32] fp32, pre-zeroed
{
    __shared__ f16 lw[17 * 32 * WPITCH];     // 43520 B
    for (int t = threadIdx.x; t < 17 * 32 * WPITCH / 8; t += 256)
        reinterpret_cast<short8*>(lw)[t] = reinterpret_cast<const short8*>(Wbt)[t];
    __syncthreads();

    int wave = threadIdx.x >> 6;
    int lane = threadIdx.x & 63;
    int job  = blockIdx.x * 4 + wave;
    if (job >= NJOBS) return;

    int col  = lane & 15;        // A-row select / D-col (i)
    int kg   = lane >> 4;        // k-group: j = kg*8..kg*8+7
    int row0 = kg * 4;           // D rows held by this lane

    int base0 = job * 32;        // tile0 edges base0.., tile1 edges base0+16..
    int e0 = base0 + col;
    int e1 = base0 + 16 + col;

    int2 p0 = reinterpret_cast<const int2*>(pair)[e0];
    int2 p1 = reinterpret_cast<const int2*>(pair)[e1];

    half8 hf0 = *reinterpret_cast<const half8*>(hb + (size_t)p0.y * 32 + kg * 8);
    half8 hf1 = *reinterpret_cast<const half8*>(hb + (size_t)p1.y * 32 + kg * 8);

    float c0[16], c1[16];
    {
        const float4* b4 = reinterpret_cast<const float4*>(bond + (size_t)e0 * 16);
        float4 t0 = b4[0], t1 = b4[1], t2 = b4[2], t3 = b4[3];
        c0[0]=t0.x; c0[1]=t0.y; c0[2]=t0.z; c0[3]=t0.w;
        c0[4]=t1.x; c0[5]=t1.y; c0[6]=t1.z; c0[7]=t1.w;
        c0[8]=t2.x; c0[9]=t2.y; c0[10]=t2.z; c0[11]=t2.w;
        c0[12]=t3.x; c0[13]=t3.y; c0[14]=t3.z; c0[15]=t3.w;
        const float4* b5 = reinterpret_cast<const float4*>(bond + (size_t)e1 * 16);
        float4 u0 = b5[0], u1 = b5[1], u2 = b5[2], u3 = b5[3];
        c1[0]=u0.x; c1[1]=u0.y; c1[2]=u0.z; c1[3]=u0.w;
        c1[4]=u1.x; c1[5]=u1.y; c1[6]=u1.z; c1[7]=u1.w;
        c1[8]=u2.x; c1[9]=u2.y; c1[10]=u2.z; c1[11]=u2.w;
        c1[12]=u3.x; c1[13]=u3.y; c1[14]=u3.z; c1[15]=u3.w;
    }

    f32x4 acc00 = {0.f,0.f,0.f,0.f}, acc01 = {0.f,0.f,0.f,0.f};
    f32x4 acc10 = {0.f,0.f,0.f,0.f}, acc11 = {0.f,0.f,0.f,0.f};

#pragma unroll
    for (int s = 0; s < 16; ++s) {
        half8 b0 = *reinterpret_cast<const half8*>(lw + (s * 32 + col) * WPITCH + kg * 8);
        half8 b1 = *reinterpret_cast<const half8*>(lw + (s * 32 + 16 + col) * WPITCH + kg * 8);
        f16 ch0 = (f16)c0[s];
        f16 ch1 = (f16)c1[s];
        half8 a0 = hf0 * ch0;          // v_pk_mul_f16 x4
        half8 a1 = hf1 * ch1;
        acc00 = __builtin_amdgcn_mfma_f32_16x16x32_f16(a0, b0, acc00, 0, 0, 0);
        acc01 = __builtin_amdgcn_mfma_f32_16x16x32_f16(a0, b1, acc01, 0, 0, 0);
        acc10 = __builtin_amdgcn_mfma_f32_16x16x32_f16(a1, b0, acc10, 0, 0, 0);
        acc11 = __builtin_amdgcn_mfma_f32_16x16x32_f16(a1, b1, acc11, 0, 0, 0);
    }
    {   // bias matrix (k=16): unscaled h
        half8 b0 = *reinterpret_cast<const half8*>(lw + (16 * 32 + col) * WPITCH + kg * 8);
        half8 b1 = *reinterpret_cast<const half8*>(lw + (16 * 32 + 16 + col) * WPITCH + kg * 8);
        acc00 = __builtin_amdgcn_mfma_f32_16x16x32_f16(hf0, b0, acc00, 0, 0, 0);
        acc01 = __builtin_amdgcn_mfma_f32_16x16x32_f16(hf0, b1, acc01, 0, 0, 0);
        acc10 = __builtin_amdgcn_mfma_f32_16x16x32_f16(hf1, b0, acc10, 0, 0, 0);
        acc11 = __builtin_amdgcn_mfma_f32_16x16x32_f16(hf1, b1, acc11, 0, 0, 0);
    }

#pragma unroll
    for (int r = 0; r < 4; ++r) {
        int dr0 = __shfl(p0.x, row0 + r);
        int dr1 = __shfl(p1.x, row0 + r);
        atomicAdd(&agg[(size_t)dr0 * 32 + col],      acc00[r]);
        atomicAdd(&agg[(size_t)dr0 * 32 + 16 + col], acc01[r]);
        atomicAdd(&agg[(size_t)dr1 * 32 + col],      acc10[r]);
        atomicAdd(&agg[(size_t)dr1 * 32 + 16 + col], acc11[r]);
    }
}

// ---------------------------------------------------------------------------
// GRU via MFMA (fp16): one wave = 16 atoms, 12 independent MFMAs.
// ---------------------------------------------------------------------------
__global__ __launch_bounds__(256) void gru_kernel(
    const float* __restrict__ agg,            // [NA][32] fp32
    const float* __restrict__ hprev,          // [NA][32] fp32
    const f16* __restrict__ hb,               // [NA][32] fp16 (same h as hprev)
    const f16* __restrict__ Wihb,             // [96][32] fp16
    const f16* __restrict__ Whhb,             // [96][32] fp16
    const float* __restrict__ bih, const float* __restrict__ bhh,
    float* __restrict__ hout, f16* __restrict__ hbf)
{
    int wave = threadIdx.x >> 6;
    int lane = threadIdx.x & 63;
    int tile = blockIdx.x * 4 + wave;
    if (tile >= ATILES) return;

    int base = tile * 16;
    int col  = lane & 15;
    int kg   = lane >> 4;

    half8 xfrag;
    {
        const float4* x4 = reinterpret_cast<const float4*>(agg + (size_t)(base + col) * 32 + kg * 8);
        float4 a = x4[0], b = x4[1];
        xfrag[0] = (f16)a.x; xfrag[1] = (f16)a.y; xfrag[2] = (f16)a.z; xfrag[3] = (f16)a.w;
        xfrag[4] = (f16)b.x; xfrag[5] = (f16)b.y; xfrag[6] = (f16)b.z; xfrag[7] = (f16)b.w;
    }
    half8 hfrag = *reinterpret_cast<const half8*>(hb + (size_t)(base + col) * 32 + kg * 8);

    f32x4 gi[6], gh[6];
#pragma unroll
    for (int t = 0; t < 6; ++t) {
        half8 bi = *reinterpret_cast<const half8*>(Wihb + (size_t)(t * 16 + col) * 32 + kg * 8);
        half8 bh = *reinterpret_cast<const half8*>(Whhb + (size_t)(t * 16 + col) * 32 + kg * 8);
        f32x4 z = {0.f, 0.f, 0.f, 0.f};
        gi[t] = __builtin_amdgcn_mfma_f32_16x16x32_f16(xfrag, bi, z, 0, 0, 0);
        gh[t] = __builtin_amdgcn_mfma_f32_16x16x32_f16(hfrag, bh, z, 0, 0, 0);
    }

#pragma unroll
    for (int hh = 0; hh < 2; ++hh) {
        int i  = hh * 16 + col;
        float br  = bih[i]      + bhh[i];
        float bz  = bih[32 + i] + bhh[32 + i];
        float bin = bih[64 + i];
        float bhn = bhh[64 + i];
#pragma unroll
        for (int reg = 0; reg < 4; ++reg) {
            int a = base + kg * 4 + reg;
            float r = 1.f / (1.f + __expf(-(gi[hh][reg] + gh[hh][reg] + br)));
            float z = 1.f / (1.f + __expf(-(gi[2 + hh][reg] + gh[2 + hh][reg] + bz)));
            float n = tanhf(gi[4 + hh][reg] + bin + r * (gh[4 + hh][reg] + bhn));
            float hp = hprev[(size_t)a * 32 + i];
            float o  = (1.f - z) * n + z * hp;
            hout[(size_t)a * 32 + i] = o;
            hbf[(size_t)a * 32 + i]  = (f16)o;
        }
    }
}

extern "C" void kernel_launch(void* const* d_in, const int* in_sizes, int n_in,
                              void* d_out, int out_size, void* d_ws, size_t ws_size,
                              hipStream_t stream)
{
    const float* atom = (const float*)d_in[0];
    const float* bond = (const float*)d_in[1];
    const int*   pair = (const int*)  d_in[2];
    const float* Wb   = (const float*)d_in[3];
    const float* bb   = (const float*)d_in[4];
    const float* W_ih = (const float*)d_in[5];
    const float* W_hh = (const float*)d_in[6];
    const float* b_ih = (const float*)d_in[7];
    const float* b_hh = (const float*)d_in[8];
    float* out = (float*)d_out;

    const size_t HB = (size_t)NA * 32 * sizeof(float);      // 12.8 MB
    float* agg  = (float*)d_ws;
    float* h0   = (float*)((char*)d_ws + HB);
    float* h1   = (float*)((char*)d_ws + 2 * HB);
    f16*   hbf  = (f16*)((char*)d_ws + 3 * HB);             // 6.4 MB
    f16*   Wbt  = (f16*)((char*)d_ws + 3 * HB + HB / 2);    // 43.5 KB
    f16*   Wihb = Wbt + 17 * 32 * WPITCH;
    f16*   Whhb = Wihb + 96 * 32;
    float* hbufs[2] = { h0, h1 };

    const int conv_blocks = (NA * 32 / 4 + 255) / 256;
    const int prep_blocks = (17 * 32 * 32 + 6144 + 255) / 256;
    const int msg_blocks  = (NJOBS + 3) / 4;
    const int gru_blocks  = (ATILES + 3) / 4;

    prep_kernel<<<prep_blocks, 256, 0, stream>>>(Wb, bb, W_ih, W_hh, Wbt, Wihb, Whhb);
    conv_kernel<<<conv_blocks, 256, 0, stream>>>(atom, hbf);

    const float* hcur = atom;
    for (int s = 0; s < STEPS; ++s) {
        hipMemsetAsync(agg, 0, HB, stream);
        msg_kernel<<<msg_blocks, 256, 0, stream>>>(hbf, bond, pair, Wbt, agg);
        float* hnext = (s == STEPS - 1) ? out : hbufs[s & 1];
        gru_kernel<<<gru_blocks, 256, 0, stream>>>(agg, hcur, hbf, Wihb, Whhb,
                                                   b_ih, b_hh, hnext, hbf);
        hcur = hnext;
    }
}

// Round 7
// 271.274 us; speedup vs baseline: 19.9664x; 1.0345x over previous
//
#include <hip/hip_runtime.h>

#define NA 100000
#define NE 300000
#define STEPS 4
#define NTILES (NE / 16)        // 18750 (exact)
#define NJOBS  (NTILES / 2)     // 9375  (2 tiles per wave)
#define ATILES (NA / 16)        // 6250  (exact)
#define WPITCH 40               // padded j-pitch (elements) for Wbt rows

typedef _Float16 f16;
typedef _Float16 half8 __attribute__((ext_vector_type(8)));
using f32x4  = __attribute__((ext_vector_type(4))) float;
using short8 = __attribute__((ext_vector_type(8))) short;

// ---------------------------------------------------------------------------
// fp32 -> fp16 bulk convert (step-0 h)
// ---------------------------------------------------------------------------
__global__ __launch_bounds__(256) void conv_kernel(
    const float* __restrict__ h, f16* __restrict__ hb)
{
    int t = blockIdx.x * 256 + threadIdx.x;
    if (t >= NA * 32 / 4) return;
    float4 v = reinterpret_cast<const float4*>(h)[t];
    f16 o0 = (f16)v.x, o1 = (f16)v.y, o2 = (f16)v.z, o3 = (f16)v.w;
    ushort4 u;
    u.x = __builtin_bit_cast(unsigned short, o0);
    u.y = __builtin_bit_cast(unsigned short, o1);
    u.z = __builtin_bit_cast(unsigned short, o2);
    u.w = __builtin_bit_cast(unsigned short, o3);
    reinterpret_cast<ushort4*>(hb)[t] = u;
}

// ---------------------------------------------------------------------------
// Preconvert weights to fp16: Wbt[k][i][j] (pitch 40, k=16 is bias matrix),
// Wihb / Whhb = [96][32] row-major.
// ---------------------------------------------------------------------------
__global__ __launch_bounds__(256) void prep_kernel(
    const float* __restrict__ Wb, const float* __restrict__ bb,
    const float* __restrict__ Wih, const float* __restrict__ Whh,
    f16* __restrict__ Wbt, f16* __restrict__ Wihb, f16* __restrict__ Whhb)
{
    int t = blockIdx.x * 256 + threadIdx.x;     // < 17*32*32 + 2*96*32 = 23552
    if (t < 17 * 32 * 32) {
        int j = t & 31, i = (t >> 5) & 31, k = t >> 10;
        float v = (k < 16) ? Wb[k * 1024 + i * 32 + j] : bb[i * 32 + j];
        Wbt[(k * 32 + i) * WPITCH + j] = (f16)v;
    } else if (t < 17 * 32 * 32 + 3072) {
        int u = t - 17 * 32 * 32;
        Wihb[u] = (f16)Wih[u];
    } else if (t < 17 * 32 * 32 + 6144) {
        int u = t - 17 * 32 * 32 - 3072;
        Whhb[u] = (f16)Whh[u];
    }
}

// ---------------------------------------------------------------------------
// msg: c folded into the A-operand. One wave = 32 edges (2 tiles).
// 512-thread blocks (8 waves) amortize the 43.5 KB LDS stage and lift
// occupancy to 24 waves/CU (launch_bounds cap: VGPR<=85, no spill at 68).
// ---------------------------------------------------------------------------
__global__ __launch_bounds__(512, 6) void msg_kernel(
    const f16* __restrict__ hb,              // [NA][32] fp16
    const float* __restrict__ bond,          // [NE][16]
    const int* __restrict__ pair,            // [NE][2] (dst, nbr)
    const f16* __restrict__ Wbt,             // [17][32][WPITCH] fp16
    float* __restrict__ agg)                 // [NA][32] fp32, pre-zeroed
{
    __shared__ f16 lw[17 * 32 * WPITCH];     // 43520 B
    for (int t = threadIdx.x; t < 17 * 32 * WPITCH / 8; t += 512)
        reinterpret_cast<short8*>(lw)[t] = reinterpret_cast<const short8*>(Wbt)[t];
    __syncthreads();

    int wave = threadIdx.x >> 6;
    int lane = threadIdx.x & 63;
    int job  = blockIdx.x * 8 + wave;
    if (job >= NJOBS) return;

    int col  = lane & 15;        // A-row select / D-col (i)
    int kg   = lane >> 4;        // k-group: j = kg*8..kg*8+7
    int row0 = kg * 4;           // D rows held by this lane

    int base0 = job * 32;        // tile0 edges base0.., tile1 edges base0+16..
    int e0 = base0 + col;
    int e1 = base0 + 16 + col;

    int2 p0 = reinterpret_cast<const int2*>(pair)[e0];
    int2 p1 = reinterpret_cast<const int2*>(pair)[e1];

    half8 hf0 = *reinterpret_cast<const half8*>(hb + (size_t)p0.y * 32 + kg * 8);
    half8 hf1 = *reinterpret_cast<const half8*>(hb + (size_t)p1.y * 32 + kg * 8);

    float c0[16], c1[16];
    {
        const float4* b4 = reinterpret_cast<const float4*>(bond + (size_t)e0 * 16);
        float4 t0 = b4[0], t1 = b4[1], t2 = b4[2], t3 = b4[3];
        c0[0]=t0.x; c0[1]=t0.y; c0[2]=t0.z; c0[3]=t0.w;
        c0[4]=t1.x; c0[5]=t1.y; c0[6]=t1.z; c0[7]=t1.w;
        c0[8]=t2.x; c0[9]=t2.y; c0[10]=t2.z; c0[11]=t2.w;
        c0[12]=t3.x; c0[13]=t3.y; c0[14]=t3.z; c0[15]=t3.w;
        const float4* b5 = reinterpret_cast<const float4*>(bond + (size_t)e1 * 16);
        float4 u0 = b5[0], u1 = b5[1], u2 = b5[2], u3 = b5[3];
        c1[0]=u0.x; c1[1]=u0.y; c1[2]=u0.z; c1[3]=u0.w;
        c1[4]=u1.x; c1[5]=u1.y; c1[6]=u1.z; c1[7]=u1.w;
        c1[8]=u2.x; c1[9]=u2.y; c1[10]=u2.z; c1[11]=u2.w;
        c1[12]=u3.x; c1[13]=u3.y; c1[14]=u3.z; c1[15]=u3.w;
    }

    f32x4 acc00 = {0.f,0.f,0.f,0.f}, acc01 = {0.f,0.f,0.f,0.f};
    f32x4 acc10 = {0.f,0.f,0.f,0.f}, acc11 = {0.f,0.f,0.f,0.f};

#pragma unroll
    for (int s = 0; s < 16; ++s) {
        half8 b0 = *reinterpret_cast<const half8*>(lw + (s * 32 + col) * WPITCH + kg * 8);
        half8 b1 = *reinterpret_cast<const half8*>(lw + (s * 32 + 16 + col) * WPITCH + kg * 8);
        f16 ch0 = (f16)c0[s];
        f16 ch1 = (f16)c1[s];
        half8 a0 = hf0 * ch0;          // v_pk_mul_f16 x4
        half8 a1 = hf1 * ch1;
        acc00 = __builtin_amdgcn_mfma_f32_16x16x32_f16(a0, b0, acc00, 0, 0, 0);
        acc01 = __builtin_amdgcn_mfma_f32_16x16x32_f16(a0, b1, acc01, 0, 0, 0);
        acc10 = __builtin_amdgcn_mfma_f32_16x16x32_f16(a1, b0, acc10, 0, 0, 0);
        acc11 = __builtin_amdgcn_mfma_f32_16x16x32_f16(a1, b1, acc11, 0, 0, 0);
    }
    {   // bias matrix (k=16): unscaled h
        half8 b0 = *reinterpret_cast<const half8*>(lw + (16 * 32 + col) * WPITCH + kg * 8);
        half8 b1 = *reinterpret_cast<const half8*>(lw + (16 * 32 + 16 + col) * WPITCH + kg * 8);
        acc00 = __builtin_amdgcn_mfma_f32_16x16x32_f16(hf0, b0, acc00, 0, 0, 0);
        acc01 = __builtin_amdgcn_mfma_f32_16x16x32_f16(hf0, b1, acc01, 0, 0, 0);
        acc10 = __builtin_amdgcn_mfma_f32_16x16x32_f16(hf1, b0, acc10, 0, 0, 0);
        acc11 = __builtin_amdgcn_mfma_f32_16x16x32_f16(hf1, b1, acc11, 0, 0, 0);
    }

#pragma unroll
    for (int r = 0; r < 4; ++r) {
        int dr0 = __shfl(p0.x, row0 + r);
        int dr1 = __shfl(p1.x, row0 + r);
        atomicAdd(&agg[(size_t)dr0 * 32 + col],      acc00[r]);
        atomicAdd(&agg[(size_t)dr0 * 32 + 16 + col], acc01[r]);
        atomicAdd(&agg[(size_t)dr1 * 32 + col],      acc10[r]);
        atomicAdd(&agg[(size_t)dr1 * 32 + 16 + col], acc11[r]);
    }
}

// ---------------------------------------------------------------------------
// GRU via MFMA (fp16). Blend uses fp16 h (same buffer it rewrites — each
// atom row touched only by its own wave). fp32 hout written only at the
// final step (write_f32 flag, wave-uniform branch).
// ---------------------------------------------------------------------------
__global__ __launch_bounds__(256) void gru_kernel(
    const float* __restrict__ agg,            // [NA][32] fp32
    const f16* __restrict__ hb,               // [NA][32] fp16 (h_prev; rewritten)
    const f16* __restrict__ Wihb,             // [96][32] fp16
    const f16* __restrict__ Whhb,             // [96][32] fp16
    const float* __restrict__ bih, const float* __restrict__ bhh,
    float* __restrict__ hout, f16* __restrict__ hbf, int write_f32)
{
    int wave = threadIdx.x >> 6;
    int lane = threadIdx.x & 63;
    int tile = blockIdx.x * 4 + wave;
    if (tile >= ATILES) return;

    int base = tile * 16;
    int col  = lane & 15;
    int kg   = lane >> 4;

    half8 xfrag;
    {
        const float4* x4 = reinterpret_cast<const float4*>(agg + (size_t)(base + col) * 32 + kg * 8);
        float4 a = x4[0], b = x4[1];
        xfrag[0] = (f16)a.x; xfrag[1] = (f16)a.y; xfrag[2] = (f16)a.z; xfrag[3] = (f16)a.w;
        xfrag[4] = (f16)b.x; xfrag[5] = (f16)b.y; xfrag[6] = (f16)b.z; xfrag[7] = (f16)b.w;
    }
    half8 hfrag = *reinterpret_cast<const half8*>(hb + (size_t)(base + col) * 32 + kg * 8);

    f32x4 gi[6], gh[6];
#pragma unroll
    for (int t = 0; t < 6; ++t) {
        half8 bi = *reinterpret_cast<const half8*>(Wihb + (size_t)(t * 16 + col) * 32 + kg * 8);
        half8 bh = *reinterpret_cast<const half8*>(Whhb + (size_t)(t * 16 + col) * 32 + kg * 8);
        f32x4 z = {0.f, 0.f, 0.f, 0.f};
        gi[t] = __builtin_amdgcn_mfma_f32_16x16x32_f16(xfrag, bi, z, 0, 0, 0);
        gh[t] = __builtin_amdgcn_mfma_f32_16x16x32_f16(hfrag, bh, z, 0, 0, 0);
    }

#pragma unroll
    for (int hh = 0; hh < 2; ++hh) {
        int i  = hh * 16 + col;
        float br  = bih[i]      + bhh[i];
        float bz  = bih[32 + i] + bhh[32 + i];
        float bin = bih[64 + i];
        float bhn = bhh[64 + i];
#pragma unroll
        for (int reg = 0; reg < 4; ++reg) {
            int a = base + kg * 4 + reg;
            float r = 1.f / (1.f + __expf(-(gi[hh][reg] + gh[hh][reg] + br)));
            float z = 1.f / (1.f + __expf(-(gi[2 + hh][reg] + gh[2 + hh][reg] + bz)));
            float n = tanhf(gi[4 + hh][reg] + bin + r * (gh[4 + hh][reg] + bhn));
            float hp = (float)hb[(size_t)a * 32 + i];   // fp16 h_prev
            float o  = (1.f - z) * n + z * hp;
            if (write_f32) hout[(size_t)a * 32 + i] = o;
            hbf[(size_t)a * 32 + i] = (f16)o;
        }
    }
}

extern "C" void kernel_launch(void* const* d_in, const int* in_sizes, int n_in,
                              void* d_out, int out_size, void* d_ws, size_t ws_size,
                              hipStream_t stream)
{
    const float* atom = (const float*)d_in[0];
    const float* bond = (const float*)d_in[1];
    const int*   pair = (const int*)  d_in[2];
    const float* Wb   = (const float*)d_in[3];
    const float* bb   = (const float*)d_in[4];
    const float* W_ih = (const float*)d_in[5];
    const float* W_hh = (const float*)d_in[6];
    const float* b_ih = (const float*)d_in[7];
    const float* b_hh = (const float*)d_in[8];
    float* out = (float*)d_out;

    const size_t HB = (size_t)NA * 32 * sizeof(float);      // 12.8 MB
    float* agg  = (float*)d_ws;
    f16*   hbf  = (f16*)((char*)d_ws + HB);                 // 6.4 MB
    f16*   Wbt  = (f16*)((char*)d_ws + HB + HB / 2);        // 43.5 KB
    f16*   Wihb = Wbt + 17 * 32 * WPITCH;
    f16*   Whhb = Wihb + 96 * 32;

    const int conv_blocks = (NA * 32 / 4 + 255) / 256;
    const int prep_blocks = (17 * 32 * 32 + 6144 + 255) / 256;
    const int msg_blocks  = (NJOBS + 7) / 8;
    const int gru_blocks  = (ATILES + 3) / 4;

    prep_kernel<<<prep_blocks, 256, 0, stream>>>(Wb, bb, W_ih, W_hh, Wbt, Wihb, Whhb);
    conv_kernel<<<conv_blocks, 256, 0, stream>>>(atom, hbf);

    for (int s = 0; s < STEPS; ++s) {
        hipMemsetAsync(agg, 0, HB, stream);
        msg_kernel<<<msg_blocks, 512, 0, stream>>>(hbf, bond, pair, Wbt, agg);
        gru_kernel<<<gru_blocks, 256, 0, stream>>>(agg, hbf, Wihb, Whhb,
                                                   b_ih, b_hh, out, hbf,
                                                   (s == STEPS - 1) ? 1 : 0);
    }
}